// Round 4
// baseline (1196.019 us; speedup 1.0000x reference)
//
#include <hip/hip_runtime.h>
#include <hip/hip_bf16.h>

// TreeLSTM on MI355X. B=256 trees, 256 leaves (depth 9), H=512, X=300, 5 classes.
// ALL float tensors are FLOAT32 (per reference); wordid int32; output f32 [256,511,5].
//
// Pipeline: cvt weights (f32->bf16, pad W_iou K 300->320) -> per batch-chunk:
//   leaf (gather emb + cvt + GEMM3 + cell) -> logits(leaf)
//   -> 8x { level (GEMM5 + cell) -> logits(level) }.
// h ping-pong bf16 (feeds MFMA), c ping-pong f32. Compute: bf16 MFMA, f32 accum/cell.
// ws plans: nc=1 294MB / nc=2 151MB / nc=4 82MB, picked from ws_size (deterministic).

typedef __bf16 bf16;
typedef bf16  bf16x8 __attribute__((ext_vector_type(8)));
typedef float f32x4  __attribute__((ext_vector_type(4)));

__device__ __forceinline__ float sigm(float x){ return 1.0f/(1.0f + __expf(-x)); }
__device__ __forceinline__ float tanh_f(float x){ return 1.0f - 2.0f/(__expf(2.0f*x)+1.0f); }

// ---- convert W_iou f32[1536,300] -> bf16[1536,320] zero-padded ----
__global__ void cvt_pad_w(const float* __restrict__ src, bf16* __restrict__ dst){
  const int row = blockIdx.x, c = threadIdx.x;   // 1536 x 320 threads
  dst[row*320 + c] = (bf16)(c < 300 ? src[row*300 + c] : 0.f);
}
// ---- convert f32 -> bf16 elementwise ----
__global__ void cvt(const float* __restrict__ src, bf16* __restrict__ dst, int n){
  const int i = blockIdx.x*256 + threadIdx.x;
  if (i < n) dst[i] = (bf16)src[i];
}

// ---- leaf: x=emb[wordid]; iou = x @ W_iou^T + b; c=sig(i)tanh(u); h=sig(o)tanh(c) ----
// 256 thr = 4 waves; tile 64 rows x 64 cols (of H); 3 acc sets (i,o,u).
__global__ __launch_bounds__(256)
void leaf_kernel(const int* __restrict__ wordid, const float* __restrict__ emb,
                 const bf16* __restrict__ Wpad, const float* __restrict__ Wb,
                 bf16* __restrict__ hcur, float* __restrict__ ccur)
{
  __shared__ bf16 lsA[64*40];      // row stride 40 elems (80 B) breaks pow2 bank stride
  __shared__ bf16 lsB[3][64*40];
  const int t = threadIdx.x;
  const int mrow0 = blockIdx.x*64, nblk = blockIdx.y*64;
  const int r = t>>2, kc = (t&3)*8;                 // staging: 4 thr/row, 8 elems each
  const int lane16 = t&15, quad = (t&63)>>4, w = t>>6;

  f32x4 acc[3][4];
  const f32x4 zero = {0.f,0.f,0.f,0.f};
  #pragma unroll
  for(int o=0;o<3;o++){
    #pragma unroll
    for(int rt=0;rt<4;rt++) acc[o][rt]=zero;
  }

  const int wid = wordid[mrow0 + r];
  const float* erow = emb + (size_t)wid*300;
  const int col = nblk + r;
  for (int k0=0;k0<320;k0+=32){
    const int e = k0 + kc;
    bf16x8 v;
    #pragma unroll
    for (int i=0;i<8;i++) v[i] = (bf16)0.f;
    if (e + 8 <= 300){
      const f32x4 f0 = *(const f32x4*)(erow + e);      // 1200*wid+4e bytes: 16-aligned
      const f32x4 f1 = *(const f32x4*)(erow + e + 4);
      #pragma unroll
      for (int i=0;i<4;i++){ v[i] = (bf16)f0[i]; v[4+i] = (bf16)f1[i]; }
    } else if (e < 300){
      #pragma unroll
      for (int i=0;i<8;i++){ if (e+i < 300) v[i] = (bf16)erow[e+i]; }
    }
    *(bf16x8*)&lsA[r*40+kc] = v;
    *(bf16x8*)&lsB[0][r*40+kc] = *(const bf16x8*)&Wpad[(size_t)col*320        + k0+kc];
    *(bf16x8*)&lsB[1][r*40+kc] = *(const bf16x8*)&Wpad[(size_t)(512+col)*320  + k0+kc];
    *(bf16x8*)&lsB[2][r*40+kc] = *(const bf16x8*)&Wpad[(size_t)(1024+col)*320 + k0+kc];
    __syncthreads();
    bf16x8 bfrag[3];
    #pragma unroll
    for(int o=0;o<3;o++) bfrag[o] = *(const bf16x8*)&lsB[o][(w*16+lane16)*40 + quad*8];
    #pragma unroll
    for(int rt=0;rt<4;rt++){
      bf16x8 a = *(const bf16x8*)&lsA[(rt*16+lane16)*40 + quad*8];
      #pragma unroll
      for(int o=0;o<3;o++)
        acc[o][rt] = __builtin_amdgcn_mfma_f32_16x16x32_bf16(a, bfrag[o], acc[o][rt], 0,0,0);
    }
    __syncthreads();
  }
  const int j = nblk + w*16 + lane16;
  const float bi=Wb[j], bo=Wb[512+j], bu=Wb[1024+j];
  #pragma unroll
  for(int rt=0;rt<4;rt++){
    #pragma unroll
    for(int reg=0;reg<4;reg++){
      const int row = mrow0 + rt*16 + quad*4 + reg;   // C/D: row=quad*4+reg, col=lane16
      float iv=acc[0][rt][reg]+bi, ov=acc[1][rt][reg]+bo, uv=acc[2][rt][reg]+bu;
      float c = sigm(iv)*tanh_f(uv);
      float h = sigm(ov)*tanh_f(c);
      ccur[(size_t)row*512 + j] = c;
      hcur[(size_t)row*512 + j] = (bf16)h;
    }
  }
}

// ---- level: h_cat @ {U_iou,U_f}^T, full cell with c_f; 5 acc sets ----
// node row p: children = prev rows 2p,2p+1 (contiguous 1024 bf16 = h_cat).
__global__ __launch_bounds__(256)
void level_kernel(const bf16* __restrict__ hprev, bf16* __restrict__ hcur,
                  const float* __restrict__ cprev, float* __restrict__ ccur,
                  const bf16* __restrict__ Ubf, const float* __restrict__ Uioub,
                  const bf16* __restrict__ Ufbf, const float* __restrict__ Ufb)
{
  __shared__ bf16 lsA[64*40];
  __shared__ bf16 lsB[5][64*40];
  const int t = threadIdx.x;
  const int mrow0 = blockIdx.x*64, nblk = blockIdx.y*64;
  const int r = t>>2, kc = (t&3)*8;
  const int lane16 = t&15, quad = (t&63)>>4, w = t>>6;

  f32x4 acc[5][4];
  const f32x4 zero = {0.f,0.f,0.f,0.f};
  #pragma unroll
  for(int o=0;o<5;o++){
    #pragma unroll
    for(int rt=0;rt<4;rt++) acc[o][rt]=zero;
  }

  const bf16* arow = hprev + (size_t)(mrow0 + r)*1024;   // h_cat of node row mrow0+r
  const int col = nblk + r;
  for (int k0=0;k0<1024;k0+=32){
    *(bf16x8*)&lsA[r*40+kc]    = *(const bf16x8*)&arow[k0+kc];
    *(bf16x8*)&lsB[0][r*40+kc] = *(const bf16x8*)&Ubf[(size_t)col*1024        + k0+kc];
    *(bf16x8*)&lsB[1][r*40+kc] = *(const bf16x8*)&Ubf[(size_t)(512+col)*1024  + k0+kc];
    *(bf16x8*)&lsB[2][r*40+kc] = *(const bf16x8*)&Ubf[(size_t)(1024+col)*1024 + k0+kc];
    *(bf16x8*)&lsB[3][r*40+kc] = *(const bf16x8*)&Ufbf[(size_t)col*1024       + k0+kc];
    *(bf16x8*)&lsB[4][r*40+kc] = *(const bf16x8*)&Ufbf[(size_t)(512+col)*1024 + k0+kc];
    __syncthreads();
    bf16x8 bfrag[5];
    #pragma unroll
    for(int o=0;o<5;o++) bfrag[o] = *(const bf16x8*)&lsB[o][(w*16+lane16)*40 + quad*8];
    #pragma unroll
    for(int rt=0;rt<4;rt++){
      bf16x8 a = *(const bf16x8*)&lsA[(rt*16+lane16)*40 + quad*8];
      #pragma unroll
      for(int o=0;o<5;o++)
        acc[o][rt] = __builtin_amdgcn_mfma_f32_16x16x32_bf16(a, bfrag[o], acc[o][rt], 0,0,0);
    }
    __syncthreads();
  }
  const int j = nblk + w*16 + lane16;
  const float bi =Uioub[j], bo=Uioub[512+j], bu=Uioub[1024+j];
  const float bfl=Ufb[j],   bfr=Ufb[512+j];
  #pragma unroll
  for(int rt=0;rt<4;rt++){
    #pragma unroll
    for(int reg=0;reg<4;reg++){
      const int row = mrow0 + rt*16 + quad*4 + reg;
      float iv=acc[0][rt][reg]+bi, ov=acc[1][rt][reg]+bo, uv=acc[2][rt][reg]+bu;
      float fl=acc[3][rt][reg]+bfl, fr=acc[4][rt][reg]+bfr;
      float cl = cprev[((size_t)row*2  )*512 + j];
      float cr = cprev[((size_t)row*2+1)*512 + j];
      float cf = sigm(fl)*cl + sigm(fr)*cr;
      float c  = sigm(iv)*tanh_f(uv) + cf;
      float h  = sigm(ov)*tanh_f(c);
      ccur[(size_t)row*512 + j] = c;
      hcur[(size_t)row*512 + j] = (bf16)h;
    }
  }
}

// ---- logits for one level: out[(b*511+off+n)*5+c] = h_row . lin_w[c] + lin_b[c] ----
__global__ __launch_bounds__(256)
void logits_kernel(const bf16* __restrict__ h, const float* __restrict__ linw,
                   const float* __restrict__ linb, float* __restrict__ out,
                   int lgm, int mask, int off){
  const int row = blockIdx.x*4 + (threadIdx.x>>6);
  const int l = threadIdx.x & 63;
  bf16x8 hv = *(const bf16x8*)(h + (size_t)row*512 + l*8);
  float hf[8];
  #pragma unroll
  for(int jj=0;jj<8;jj++) hf[jj] = (float)hv[jj];
  float s[5];
  #pragma unroll
  for(int c=0;c<5;c++){
    const f32x4 w0 = *(const f32x4*)(linw + c*512 + l*8);
    const f32x4 w1 = *(const f32x4*)(linw + c*512 + l*8 + 4);
    float a = 0.f;
    #pragma unroll
    for(int jj=0;jj<4;jj++) a += hf[jj]*w0[jj] + hf[4+jj]*w1[jj];
    s[c]=a;
  }
  #pragma unroll
  for(int o=32;o>0;o>>=1){
    #pragma unroll
    for(int c=0;c<5;c++) s[c] += __shfl_down(s[c], o, 64);
  }
  if (l==0){
    const int node = (row>>lgm)*511 + off + (row & mask);
    #pragma unroll
    for(int c=0;c<5;c++) out[(size_t)node*5+c] = s[c] + linb[c];
  }
}

__global__ void zero_out(float* out, int n){
  int i = blockIdx.x*256 + threadIdx.x;
  if (i < n) out[i] = 0.f;
}

extern "C" void kernel_launch(void* const* d_in, const int* in_sizes, int n_in,
                              void* d_out, int out_size, void* d_ws, size_t ws_size,
                              hipStream_t stream)
{
  const int*   wordid = (const int*)d_in[0];
  const float* emb    = (const float*)d_in[1];
  const float* Wiou   = (const float*)d_in[2];
  const float* Wioub  = (const float*)d_in[3];
  const float* Uiou   = (const float*)d_in[4];
  const float* Uioub  = (const float*)d_in[5];
  const float* Uf     = (const float*)d_in[6];
  const float* Ufb    = (const float*)d_in[7];
  const float* linw   = (const float*)d_in[8];
  const float* linb   = (const float*)d_in[9];
  float* out = (float*)d_out;

  // weight area (chunk-independent)
  const size_t WPD  = (size_t)1536*320*2;     // Wpad bf16
  const size_t UIO  = (size_t)1536*1024*2;    // Uiou bf16
  const size_t UFB  = (size_t)1024*1024*2;    // Uf bf16
  const size_t WAREA = WPD + UIO + UFB;       // ~6.2 MB (16B-aligned pieces)

  // pick chunk count: smallest nc whose h/c buffers fit
  int nc = 0;
  for (int t = 1; t <= 4; t <<= 1){
    const size_t R = (size_t)65536 / t;       // leaf rows per chunk
    if (ws_size >= WAREA + R*4608) { nc = t; break; }   // hA R*1024 + hB R*512 + cA R*2048 + cB R*1024
  }

  char* ws = (char*)d_ws;
  bf16* Wpad = (bf16*)ws;
  bf16* Ubf  = (bf16*)(ws + WPD);
  bf16* Ufbf = (bf16*)(ws + WPD + UIO);

  if (nc == 0){
    zero_out<<<(out_size+255)/256, 256, 0, stream>>>(out, out_size);  // diagnostic fallback
    return;
  }

  cvt_pad_w<<<1536, 320, 0, stream>>>(Wiou, Wpad);
  cvt<<<(1536*1024+255)/256, 256, 0, stream>>>(Uiou, Ubf, 1536*1024);
  cvt<<<(1024*1024+255)/256, 256, 0, stream>>>(Uf, Ufbf, 1024*1024);

  const size_t R  = (size_t)65536 / nc;       // leaf rows per chunk
  const int   Bc  = 256 / nc;                 // trees per chunk
  bf16*  hA = (bf16*)(ws + WAREA);
  bf16*  hB = (bf16*)(ws + WAREA + R*1024);
  float* cA = (float*)(ws + WAREA + R*1024 + R*512);
  float* cB = (float*)(ws + WAREA + R*1024 + R*512 + R*2048);

  const int offs[9] = {0,256,384,448,480,496,504,508,510};
  for (int ch = 0; ch < nc; ch++){
    const int*  wid = wordid + (size_t)ch*R;
    float*      och = out + (size_t)ch*Bc*511*5;
    leaf_kernel<<<dim3((int)(R/64), 8), 256, 0, stream>>>(wid, emb, Wpad, Wioub, hA, cA);
    logits_kernel<<<(int)(R/4), 256, 0, stream>>>(hA, linw, linb, och, 8, 255, 0);
    for (int l=1;l<=8;l++){
      const int m = 256>>l, lgm = 8-l, rows = Bc*m;
      const bf16*  hin = (l&1)? hA : hB;  bf16*  hout = (l&1)? hB : hA;
      const float* cin = (l&1)? cA : cB;  float* cout = (l&1)? cB : cA;
      level_kernel<<<dim3(rows/64, 8), 256, 0, stream>>>(hin, hout, cin, cout,
                                                         Ubf, Uioub, Ufbf, Ufb);
      logits_kernel<<<rows/4, 256, 0, stream>>>(hout, linw, linb, och, lgm, m-1, offs[l]);
    }
  }
}